// Round 1
// baseline (297.383 us; speedup 1.0000x reference)
//
#include <hip/hip_runtime.h>

typedef __attribute__((ext_vector_type(8))) short bf16x8;
typedef __attribute__((ext_vector_type(4))) float f32x4;

#define NBLK   16          // nodes per tile
#define DIMF   1152        // floats per node row
#define NTILE  6250        // 100000 / 16, exact
#define GRIDSZ 1024
#define ROWU   1160        // padded ushort stride per node row (1152 + 8) -> bank spread

// round-to-nearest-even f32 -> bf16 bits (no NaNs in this data)
static __device__ __forceinline__ unsigned short f2bf(float f) {
    unsigned int u = __builtin_bit_cast(unsigned int, f);
    return (unsigned short)((u + 0x7FFFu + ((u >> 16) & 1u)) >> 16);
}

__global__ __launch_bounds__(512, 2)
void seglin_kernel(const float* __restrict__ x, const float* __restrict__ w,
                   const float* __restrict__ b, float* __restrict__ out) {
    __shared__ unsigned short xs[2][NBLK][ROWU];

    const int tid  = threadIdx.x;
    const int wv   = tid >> 6;        // wave 0..7 -> owns v rows [16*wv, 16*wv+16)
    const int lane = tid & 63;
    const int lq   = lane & 15;       // n (B col) for inputs; also A row (v) for W frags
    const int lg   = lane >> 4;       // k-group 0..3
    const int v0   = wv * 16;

    // ---- hoist A = W^T fragments into registers (once per block) ----
    // A[m=v][k=u]: lane lq = v_local, k = 32t + lg*8 + e ; value = W[u][v] = w[off + u*128 + v]
    bf16x8 wf[3][4];
    const int woff[3] = {0, 16384, 32768};
    #pragma unroll
    for (int s = 0; s < 3; ++s) {
        #pragma unroll
        for (int t = 0; t < 4; ++t) {
            bf16x8 f;
            #pragma unroll
            for (int e = 0; e < 8; ++e) {
                int u = 32 * t + lg * 8 + e;
                f[e] = (short)f2bf(w[woff[s] + u * 128 + v0 + lq]);
            }
            wf[s][t] = f;
        }
    }

    float biasr[4];
    #pragma unroll
    for (int e = 0; e < 4; ++e) biasr[e] = b[v0 + lg * 4 + e];

    const float pw = 0.08838834764831845f;  // 128^-0.5

    // ---- prologue: stage first tile into buffer 0 ----
    float4 stg[9];
    long tile = blockIdx.x;
    {
        const float* src = x + tile * (long)(NBLK * DIMF);
        #pragma unroll
        for (int it = 0; it < 9; ++it)
            stg[it] = reinterpret_cast<const float4*>(src)[it * 512 + tid];
        #pragma unroll
        for (int it = 0; it < 9; ++it) {
            int fl = (it * 512 + tid) * 4;
            int n  = fl / DIMF;
            int j  = fl - n * DIMF;
            ushort4 h;
            h.x = f2bf(stg[it].x); h.y = f2bf(stg[it].y);
            h.z = f2bf(stg[it].z); h.w = f2bf(stg[it].w);
            *reinterpret_cast<ushort4*>(&xs[0][n][j]) = h;
        }
    }
    __syncthreads();

    int cur = 0;
    for (; tile < NTILE; tile += GRIDSZ) {
        const long nxt = tile + GRIDSZ;
        const bool has_next = nxt < NTILE;

        // T14: issue next tile's global loads early; they stream during compute
        if (has_next) {
            const float* src = x + nxt * (long)(NBLK * DIMF);
            #pragma unroll
            for (int it = 0; it < 9; ++it)
                stg[it] = reinterpret_cast<const float4*>(src)[it * 512 + tid];
        }

        // ---- compute from xs[cur] ----
        f32x4 acc[9];
        #pragma unroll
        for (int q = 0; q < 9; ++q) {
            f32x4 z = {0.f, 0.f, 0.f, 0.f};
            acc[q] = z;
        }

        const unsigned short* row = &xs[cur][lq][0];
        #pragma unroll
        for (int t = 0; t < 4; ++t) {
            const int u0 = 32 * t + lg * 8;
            // segment 0 (d=1): 8 consecutive u -> one ds_read_b128
            {
                bf16x8 bf = *reinterpret_cast<const bf16x8*>(row + u0);
                acc[0] = __builtin_amdgcn_mfma_f32_16x16x32_bf16(wf[0][t], bf, acc[0], 0, 0, 0);
            }
            // segment 1 (d=3, float offset 128)
            #pragma unroll
            for (int i = 0; i < 3; ++i) {
                bf16x8 bf;
                #pragma unroll
                for (int e = 0; e < 8; ++e)
                    bf[e] = (short)row[128 + (u0 + e) * 3 + i];
                acc[1 + i] = __builtin_amdgcn_mfma_f32_16x16x32_bf16(wf[1][t], bf, acc[1 + i], 0, 0, 0);
            }
            // segment 2 (d=5, float offset 512)
            #pragma unroll
            for (int i = 0; i < 5; ++i) {
                bf16x8 bf;
                #pragma unroll
                for (int e = 0; e < 8; ++e)
                    bf[e] = (short)row[512 + (u0 + e) * 5 + i];
                acc[4 + i] = __builtin_amdgcn_mfma_f32_16x16x32_bf16(wf[2][t], bf, acc[4 + i], 0, 0, 0);
            }
        }

        // ---- epilogue: D[row=(lg*4+e) -> v_local][col=lq -> n]  (m89 layout) ----
        {
            float* orow = out + (tile * NBLK + lq) * (long)DIMF;
            const int vb = v0 + lg * 4;
            float4 o0;
            o0.x = acc[0][0] * pw + biasr[0];
            o0.y = acc[0][1] * pw + biasr[1];
            o0.z = acc[0][2] * pw + biasr[2];
            o0.w = acc[0][3] * pw + biasr[3];
            *reinterpret_cast<float4*>(orow + vb) = o0;   // seg0: v stride 1 -> dwordx4
            #pragma unroll
            for (int i = 0; i < 3; ++i)
                #pragma unroll
                for (int e = 0; e < 4; ++e)
                    orow[128 + (vb + e) * 3 + i] = acc[1 + i][e] * pw;
            #pragma unroll
            for (int i = 0; i < 5; ++i)
                #pragma unroll
                for (int e = 0; e < 4; ++e)
                    orow[512 + (vb + e) * 5 + i] = acc[4 + i][e] * pw;
        }

        // ---- convert + write next tile into the other buffer ----
        if (has_next) {
            #pragma unroll
            for (int it = 0; it < 9; ++it) {
                int fl = (it * 512 + tid) * 4;
                int n  = fl / DIMF;
                int j  = fl - n * DIMF;
                ushort4 h;
                h.x = f2bf(stg[it].x); h.y = f2bf(stg[it].y);
                h.z = f2bf(stg[it].z); h.w = f2bf(stg[it].w);
                *reinterpret_cast<ushort4*>(&xs[cur ^ 1][n][j]) = h;
            }
        }
        __syncthreads();
        cur ^= 1;
    }
}

extern "C" void kernel_launch(void* const* d_in, const int* in_sizes, int n_in,
                              void* d_out, int out_size, void* d_ws, size_t ws_size,
                              hipStream_t stream) {
    const float* x = (const float*)d_in[0];
    const float* w = (const float*)d_in[1];
    const float* b = (const float*)d_in[2];
    float* outp = (float*)d_out;
    seglin_kernel<<<dim3(GRIDSZ), dim3(512), 0, stream>>>(x, w, b, outp);
}